// Round 10
// baseline (196.304 us; speedup 1.0000x reference)
//
#include <hip/hip_runtime.h>
#include <hip/hip_fp16.h>
#include <math.h>

#define Bv 4096
#define Sv 64
#define Ev 128
#define Hv 256
#define Cv 18
#define Mrows 16
#define WRDS 4096    // words per step buffer: AH kb0..11 | A8 pairs p0..3 at 3072

typedef _Float16 hfrag __attribute__((ext_vector_type(8)));
using f4v = __attribute__((ext_vector_type(4))) float;

#define FP8_WSCALE 1048576.0f            // 2^20 on w_lo
#define FP8_ASCALE 8.0f                  // 2^3 on a
#define FP8_DESCALE (1.0f / 8388608.0f)  // 2^-23

// XOR swizzle: flips bits 2-4 by a hash of higher bits. Bits 0-1 preserved
// -> b128/uint4/uint2 contiguity kept; balances scattered writes across banks
// while reads remain the canonical conflict-free lane*16B pattern.
__device__ inline int SW(int o) {
    return o ^ ((((o >> 5) ^ (o >> 8)) & 7) << 2);
}

__device__ inline float fast_tanh(float x) {
    float e = __expf(x + x);
    return 1.0f - 2.0f * __builtin_amdgcn_rcpf(e + 1.0f);
}

__device__ inline unsigned pk_h2(float a, float b) {
    unsigned ua = __half_as_ushort(__float2half_rn(a));
    unsigned ub = __half_as_ushort(__float2half_rn(b));
    return ua | (ub << 16);
}

__device__ inline unsigned pk_fp8x4(float a, float b, float c, float d, float s) {
    int r = __builtin_amdgcn_cvt_pk_fp8_f32(a * s, b * s, 0, false);
    r = __builtin_amdgcn_cvt_pk_fp8_f32(c * s, d * s, r, true);
    return (unsigned)r;
}

__device__ inline long mklong(unsigned lo, unsigned hi) {
    return (long)(((unsigned long)hi << 32) | (unsigned long)lo);
}

// ---- kernel A: build MFMA fragments (fp16 hi + fp8 lo) for rnn W and fc W1 ----
__global__ void build_frags(const float* __restrict__ W_ih,
                            const float* __restrict__ W_hh,
                            const float* __restrict__ W1,
                            unsigned* __restrict__ wfh,  unsigned* __restrict__ wfl8,
                            unsigned* __restrict__ wf1h, unsigned* __restrict__ wf1l8) {
    int f = blockIdx.x * 256 + threadIdx.x;   // 0..20479
    bool isrnn = f < 12288;
    int g = isrnn ? f : f - 12288;
    int lane = g & 63, tile = (g >> 6) & 15, kb = g >> 10;
    int q = lane >> 4, col = lane & 15;
    int n = tile * 16 + col;
    unsigned hu[8]; float lf[8];
    #pragma unroll
    for (int j = 0; j < 8; ++j) {
        int k = kb * 32 + q * 8 + j;
        float x;
        if (isrnn) x = (k < Ev) ? W_ih[n * Ev + k] : W_hh[n * Hv + (k - Ev)];
        else       x = W1[n * Hv + k];
        __half h = __float2half_rn(x);
        hu[j] = __half_as_ushort(h);
        lf[j] = x - __half2float(h);
    }
    unsigned* oh = (isrnn ? wfh : wf1h) + (size_t)g * 4;
    unsigned* ol = (isrnn ? wfl8 : wf1l8) + (size_t)g * 2;
    #pragma unroll
    for (int d = 0; d < 4; ++d) oh[d] = hu[2 * d] | (hu[2 * d + 1] << 16);
    ol[0] = pk_fp8x4(lf[0], lf[1], lf[2], lf[3], FP8_WSCALE);
    ol[1] = pk_fp8x4(lf[4], lf[5], lf[6], lf[7], FP8_WSCALE);
}

// ---- kernel B: fused recurrence + FC head; 4 waves x 4 N-tiles, W pinned ----
__global__ __launch_bounds__(256, 1) void rnn_fused(
    const int* __restrict__ x_in, const int* __restrict__ x_len,
    const float* __restrict__ emb,
    const unsigned* __restrict__ wfh, const unsigned* __restrict__ wfl8,
    const unsigned* __restrict__ wf1h, const unsigned* __restrict__ wf1l8,
    const float* __restrict__ b_ih, const float* __restrict__ b_hh,
    const float* __restrict__ b1, const float* __restrict__ W2,
    const float* __restrict__ b2, float* __restrict__ out)
{
    __shared__ unsigned SH[2 * WRDS];   // 32 KB step buffers
    __shared__ unsigned LF[3072];       // 12 KB last-h fragments (AH 8*256 | A8 4*256)
    __shared__ int sidx[Mrows * Sv];    // 4 KB token ids, [t*16 + m]
    float* yb = reinterpret_cast<float*>(SH);   // fc y buffer aliases SH after loop

    const int tid = threadIdx.x;
    const int lane = tid & 63, w = tid >> 6;     // wave 0..3
    const int q = lane >> 4, col = lane & 15;
    const int rb = blockIdx.x * Mrows;

    // resident W: tiles 4w..4w+3 -> fp16 hi all 12 kb (192 regs) + fp8 lo kb4..11 (64)
    hfrag wh[4][12];
    long  wl8[4][8];
    #pragma unroll
    for (int i = 0; i < 4; ++i) {
        const int ti = 4 * w + i;
        #pragma unroll
        for (int kb = 0; kb < 12; ++kb) {
            int fid = (kb * 16 + ti) * 64 + lane;
            wh[i][kb] = *reinterpret_cast<const hfrag*>(&wfh[(size_t)fid * 4]);
        }
        #pragma unroll
        for (int kp = 0; kp < 8; ++kp) {
            int fid = ((kp + 4) * 16 + ti) * 64 + lane;
            wl8[i][kp] = *reinterpret_cast<const long*>(&wfl8[(size_t)fid * 2]);
        }
    }
    #pragma unroll
    for (int i = 0; i < 4; ++i) {
        #pragma unroll
        for (int kb = 0; kb < 12; ++kb) asm volatile("" : "+v"(wh[i][kb]));
        #pragma unroll
        for (int kp = 0; kp < 8; ++kp) asm volatile("" : "+v"(wl8[i][kp]));
    }

    // bias folded into MFMA C-init
    f4v bcv[4];
    #pragma unroll
    for (int i = 0; i < 4; ++i)
        #pragma unroll
        for (int r = 0; r < 4; ++r) {
            int n = (4 * w + i) * 16 + 4 * q + r;
            bcv[i][r] = b_ih[n] + b_hh[n];
        }
    const int len_c = x_len[rb + col];
    int tmax = len_c;
    #pragma unroll
    for (int m = 1; m < 16; m <<= 1) {
        int o = __shfl_xor(tmax, m, 64);
        tmax = tmax > o ? tmax : o;
    }

    // token table, transposed [t*16 + m]
    for (int u = tid; u < Mrows * Sv; u += 256) {
        int tt = u & 63, m = u >> 6;
        sidx[tt * 16 + m] = x_in[(rb + m) * Sv + tt];
    }
    // zero h region of buffer 0: AH kb4..11 (words 1024..3071) + A8 (3072..4095)
    for (int u = tid; u < 3072; u += 256) SH[1024 + u] = 0u;

    // emb staging: thread stages 8 consecutive k of one row = one full lane-frag
    const int em = tid >> 4;             // row 0..15
    const int ek = (tid & 15) * 8;       // k 0..120
    const int eo = (ek >> 5) * 256 + ((((ek >> 3) & 3) * 16 + em) * 4);

    // stage emb for t=0; prefetch row for t=1
    {
        int tok0 = x_in[(rb + em) * Sv + 0];
        const float4* ep = (const float4*)&emb[(size_t)tok0 * Ev + ek];
        float4 a = ep[0], b = ep[1];
        *reinterpret_cast<uint4*>(&SH[SW(eo)]) =
            make_uint4(pk_h2(a.x, a.y), pk_h2(a.z, a.w), pk_h2(b.x, b.y), pk_h2(b.z, b.w));
    }
    float4 evA, evB;
    {
        int tok1 = x_in[(rb + em) * Sv + 1];
        const float4* ep = (const float4*)&emb[(size_t)tok1 * Ev + ek];
        evA = ep[0]; evB = ep[1];
    }
    __syncthreads();

    #pragma unroll 1
    for (int t = 0; t < tmax; ++t) {
        const int rbuf = (t & 1) * WRDS;
        const int wbuf = ((t + 1) & 1) * WRDS;

        // prefetch emb row for t+2
        float4 enA, enB;
        if (t + 2 < Sv) {
            int tok = sidx[(t + 2) * 16 + em];
            const float4* ep = (const float4*)&emb[(size_t)tok * Ev + ek];
            enA = ep[0]; enB = ep[1];
        }

        // 12 accumulator chains: hi even/odd kb per tile + fp8 per tile
        f4v aHe[4], aHo[4], a8c[4];
        f4v z = {0.f, 0.f, 0.f, 0.f};
        #pragma unroll
        for (int i = 0; i < 4; ++i) { aHe[i] = bcv[i]; aHo[i] = z; a8c[i] = z; }

        #pragma unroll
        for (int kb = 0; kb < 4; ++kb) {
            hfrag ah = *reinterpret_cast<const hfrag*>(&SH[rbuf + SW(kb * 256 + lane * 4)]);
            if (kb & 1) {
                #pragma unroll
                for (int i = 0; i < 4; ++i)
                    aHo[i] = __builtin_amdgcn_mfma_f32_16x16x32_f16(wh[i][kb], ah, aHo[i], 0, 0, 0);
            } else {
                #pragma unroll
                for (int i = 0; i < 4; ++i)
                    aHe[i] = __builtin_amdgcn_mfma_f32_16x16x32_f16(wh[i][kb], ah, aHe[i], 0, 0, 0);
            }
        }
        #pragma unroll
        for (int p = 0; p < 4; ++p) {
            const int kbE = 4 + 2 * p;
            hfrag ahE = *reinterpret_cast<const hfrag*>(&SH[rbuf + SW(kbE * 256 + lane * 4)]);
            hfrag ahO = *reinterpret_cast<const hfrag*>(&SH[rbuf + SW((kbE + 1) * 256 + lane * 4)]);
            uint4 a8p = *reinterpret_cast<const uint4*>(&SH[rbuf + SW(3072 + p * 256 + lane * 4)]);
            long a8E = mklong(a8p.x, a8p.y), a8O = mklong(a8p.z, a8p.w);
            #pragma unroll
            for (int i = 0; i < 4; ++i)
                aHe[i] = __builtin_amdgcn_mfma_f32_16x16x32_f16(wh[i][kbE], ahE, aHe[i], 0, 0, 0);
            #pragma unroll
            for (int i = 0; i < 4; ++i)
                a8c[i] = __builtin_amdgcn_mfma_f32_16x16x32_fp8_fp8(wl8[i][2 * p], a8E, a8c[i], 0, 0, 0);
            #pragma unroll
            for (int i = 0; i < 4; ++i)
                aHo[i] = __builtin_amdgcn_mfma_f32_16x16x32_f16(wh[i][kbE + 1], ahO, aHo[i], 0, 0, 0);
            #pragma unroll
            for (int i = 0; i < 4; ++i)
                a8c[i] = __builtin_amdgcn_mfma_f32_16x16x32_fp8_fp8(wl8[i][2 * p + 1], a8O, a8c[i], 0, 0, 0);
        }

        // epilogue: lane holds h[m=col][n = ti*16 + 4q + r]
        #pragma unroll
        for (int i = 0; i < 4; ++i) {
            const int ti = 4 * w + i;
            float hv[4];
            #pragma unroll
            for (int r = 0; r < 4; ++r)
                hv[r] = fast_tanh(aHe[i][r] + aHo[i][r] + a8c[i][r] * FP8_DESCALE);
            const int dl = ((ti & 1) * 2 + (q >> 1)) * 16 + col;
            const uint2 hu = make_uint2(pk_h2(hv[0], hv[1]), pk_h2(hv[2], hv[3]));
            const unsigned a8w = pk_fp8x4(hv[0], hv[1], hv[2], hv[3], FP8_ASCALE);
            const int oAH = (4 + (ti >> 1)) * 256 + dl * 4 + (q & 1) * 2;
            const int oA8 = 3072 + (ti >> 2) * 256 + dl * 4 + ((ti >> 1) & 1) * 2 + (q & 1);
            *reinterpret_cast<uint2*>(&SH[wbuf + SW(oAH)]) = hu;
            SH[wbuf + SW(oA8)] = a8w;
            if (t == len_c - 1) {
                const int oLH = (ti >> 1) * 256 + dl * 4 + (q & 1) * 2;
                const int oL8 = 2048 + (ti >> 2) * 256 + dl * 4 + ((ti >> 1) & 1) * 2 + (q & 1);
                *reinterpret_cast<uint2*>(&LF[SW(oLH)]) = hu;
                LF[SW(oL8)] = a8w;
            }
        }
        // stage emb for step t+1 (prefetched at t-1)
        if (t + 1 < Sv) {
            *reinterpret_cast<uint4*>(&SH[wbuf + SW(eo)]) =
                make_uint4(pk_h2(evA.x, evA.y), pk_h2(evA.z, evA.w),
                           pk_h2(evB.x, evB.y), pk_h2(evB.z, evB.w));
        }
        evA = enA; evB = enB;
        __syncthreads();
    }

    // ---- fused FC1 (MFMA, fp16+fp8) on LF ----
    f4v fH[4], f8[4];
    #pragma unroll
    for (int i = 0; i < 4; ++i) {
        float4 bb = *(const float4*)&b1[(4 * w + i) * 16 + 4 * q];
        fH[i] = (f4v){bb.x, bb.y, bb.z, bb.w};
        f4v z = {0.f, 0.f, 0.f, 0.f};
        f8[i] = z;
    }
    uint4 a8p;
    #pragma unroll
    for (int kb = 0; kb < 8; ++kb) {
        hfrag ah = *reinterpret_cast<const hfrag*>(&LF[SW(kb * 256 + lane * 4)]);
        if ((kb & 1) == 0)
            a8p = *reinterpret_cast<const uint4*>(&LF[SW(2048 + (kb >> 1) * 256 + lane * 4)]);
        long a8 = (kb & 1) ? mklong(a8p.z, a8p.w) : mklong(a8p.x, a8p.y);
        #pragma unroll
        for (int i = 0; i < 4; ++i) {
            int fid = (kb * 16 + (4 * w + i)) * 64 + lane;
            hfrag w1h = *reinterpret_cast<const hfrag*>(&wf1h[(size_t)fid * 4]);
            long  w1l = *reinterpret_cast<const long*>(&wf1l8[(size_t)fid * 2]);
            fH[i] = __builtin_amdgcn_mfma_f32_16x16x32_f16(w1h, ah, fH[i], 0, 0, 0);
            f8[i] = __builtin_amdgcn_mfma_f32_16x16x32_fp8_fp8(w1l, a8, f8[i], 0, 0, 0);
        }
    }

    // y = relu(...) into yb (aliases SH; step buffers dead here)
    #pragma unroll
    for (int i = 0; i < 4; ++i) {
        int n0 = (4 * w + i) * 16 + 4 * q;
        float4 yv;
        yv.x = fmaxf(fH[i][0] + f8[i][0] * FP8_DESCALE, 0.f);
        yv.y = fmaxf(fH[i][1] + f8[i][1] * FP8_DESCALE, 0.f);
        yv.z = fmaxf(fH[i][2] + f8[i][2] * FP8_DESCALE, 0.f);
        yv.w = fmaxf(fH[i][3] + f8[i][3] * FP8_DESCALE, 0.f);
        *reinterpret_cast<float4*>(&yb[col * 260 + n0]) = yv;
    }
    __syncthreads();

    // ---- FC2: 16 x 18 dots of length 256 ----
    for (int p = tid; p < Mrows * Cv; p += 256) {
        int r = p & 15, cc = p >> 4;
        float s = b2[cc];
        #pragma unroll 8
        for (int k4 = 0; k4 < Hv / 4; ++k4) {
            float4 yv = *reinterpret_cast<const float4*>(&yb[r * 260 + 4 * k4]);
            float4 wv2 = *(const float4*)&W2[cc * Hv + 4 * k4];
            s = fmaf(yv.x, wv2.x, s);
            s = fmaf(yv.y, wv2.y, s);
            s = fmaf(yv.z, wv2.z, s);
            s = fmaf(yv.w, wv2.w, s);
        }
        out[(rb + r) * Cv + cc] = s;
    }
}

extern "C" void kernel_launch(void* const* d_in, const int* in_sizes, int n_in,
                              void* d_out, int out_size, void* d_ws, size_t ws_size,
                              hipStream_t stream) {
    const int*   x_in  = (const int*)  d_in[0];
    const int*   x_len = (const int*)  d_in[1];
    const float* emb   = (const float*)d_in[2];
    const float* W_ih  = (const float*)d_in[3];
    const float* W_hh  = (const float*)d_in[4];
    const float* b_ih  = (const float*)d_in[5];
    const float* b_hh  = (const float*)d_in[6];
    const float* W1    = (const float*)d_in[7];
    const float* b1    = (const float*)d_in[8];
    const float* W2    = (const float*)d_in[9];
    const float* b2    = (const float*)d_in[10];
    float* out = (float*)d_out;

    unsigned* wfh   = (unsigned*)d_ws;        // 12288 frags * 16 B
    unsigned* wfl8  = wfh + 12288 * 4;        // 12288 * 8 B
    unsigned* wf1h  = wfl8 + 12288 * 2;       // 8192 * 16 B
    unsigned* wf1l8 = wf1h + 8192 * 4;        // 8192 * 8 B

    build_frags<<<80, 256, 0, stream>>>(W_ih, W_hh, W1, wfh, wfl8, wf1h, wf1l8);
    rnn_fused<<<Bv / Mrows, 256, 0, stream>>>(x_in, x_len, emb, wfh, wfl8,
                                              wf1h, wf1l8, b_ih, b_hh,
                                              b1, W2, b2, out);
}

// Round 11
// 164.127 us; speedup vs baseline: 1.1961x; 1.1961x over previous
//
#include <hip/hip_runtime.h>
#include <hip/hip_fp16.h>
#include <math.h>

#define Bv 4096
#define Sv 64
#define Ev 128
#define Hv 256
#define Cv 18
#define Mrows 16
#define WRDS 3072    // words per step buffer: AH kb0..11 (emb kb0-3, h kb4-11)

typedef _Float16 hfrag __attribute__((ext_vector_type(8)));
using f4v = __attribute__((ext_vector_type(4))) float;

#define LO_SCALE 2048.0f            // 2^11 on w_lo
#define LO_DESCALE (1.0f / 2048.0f)

// XOR swizzle: flips bits 2-4 by a hash of higher bits. Bits 0-1 preserved
// -> b128/uint4/uint2 contiguity kept; balances scattered writes across banks
// while reads remain the canonical conflict-free lane*16B pattern.
__device__ inline int SW(int o) {
    return o ^ ((((o >> 5) ^ (o >> 8)) & 7) << 2);
}

__device__ inline float fast_tanh(float x) {
    float e = __expf(x + x);
    return 1.0f - 2.0f * __builtin_amdgcn_rcpf(e + 1.0f);
}

__device__ inline unsigned pk_h2(float a, float b) {
    unsigned ua = __half_as_ushort(__float2half_rn(a));
    unsigned ub = __half_as_ushort(__float2half_rn(b));
    return ua | (ub << 16);
}

// ---- kernel A: build MFMA fragments (f16 hi + f16 lo*2^11) for rnn W and W1 ----
__global__ void build_frags(const float* __restrict__ W_ih,
                            const float* __restrict__ W_hh,
                            const float* __restrict__ W1,
                            unsigned* __restrict__ wfh,  unsigned* __restrict__ wfl,
                            unsigned* __restrict__ wf1h, unsigned* __restrict__ wf1l) {
    int f = blockIdx.x * 256 + threadIdx.x;   // 0..20479
    bool isrnn = f < 12288;
    int g = isrnn ? f : f - 12288;
    int lane = g & 63, tile = (g >> 6) & 15, kb = g >> 10;
    int q = lane >> 4, col = lane & 15;
    int n = tile * 16 + col;
    unsigned hu[8], lu[8];
    #pragma unroll
    for (int j = 0; j < 8; ++j) {
        int k = kb * 32 + q * 8 + j;
        float x;
        if (isrnn) x = (k < Ev) ? W_ih[n * Ev + k] : W_hh[n * Hv + (k - Ev)];
        else       x = W1[n * Hv + k];
        __half h = __float2half_rn(x);
        hu[j] = __half_as_ushort(h);
        float l = (x - __half2float(h)) * LO_SCALE;
        lu[j] = __half_as_ushort(__float2half_rn(l));
    }
    unsigned* oh = (isrnn ? wfh : wf1h) + (size_t)g * 4;
    unsigned* ol = (isrnn ? wfl : wf1l) + (size_t)g * 4;
    #pragma unroll
    for (int d = 0; d < 4; ++d) {
        oh[d] = hu[2 * d] | (hu[2 * d + 1] << 16);
        ol[d] = lu[2 * d] | (lu[2 * d + 1] << 16);
    }
}

// ---- kernel B: fused recurrence + FC head; 8 waves x 2 N-tiles, W pinned ----
__global__ __launch_bounds__(512, 2) void rnn_fused(
    const int* __restrict__ x_in, const int* __restrict__ x_len,
    const float* __restrict__ emb,
    const unsigned* __restrict__ wfh, const unsigned* __restrict__ wfl,
    const unsigned* __restrict__ wf1h, const unsigned* __restrict__ wf1l,
    const float* __restrict__ b_ih, const float* __restrict__ b_hh,
    const float* __restrict__ b1, const float* __restrict__ W2,
    const float* __restrict__ b2, float* __restrict__ out)
{
    __shared__ unsigned SH[2 * WRDS];   // 24 KB step buffers (f16 A fragments)
    __shared__ unsigned LF[2048];       // 8 KB last-h fragments (hi only)
    __shared__ int sidx[Mrows * Sv];    // 4 KB token ids, [t*16 + m]
    float* yb = reinterpret_cast<float*>(SH);   // fc y buffer aliases SH after loop

    const int tid = threadIdx.x;
    const int lane = tid & 63, w = tid >> 6;     // wave 0..7
    const int q = lane >> 4, col = lane & 15;
    const int rb = blockIdx.x * Mrows;

    // resident W: tiles 2w, 2w+1 -> f16 hi all 12 kb (96 regs) + f16 lo kb4..11 (64)
    hfrag wh[2][12];
    hfrag wl[2][8];
    #pragma unroll
    for (int i = 0; i < 2; ++i) {
        const int ti = 2 * w + i;
        #pragma unroll
        for (int kb = 0; kb < 12; ++kb) {
            int fid = (kb * 16 + ti) * 64 + lane;
            wh[i][kb] = *reinterpret_cast<const hfrag*>(&wfh[(size_t)fid * 4]);
        }
        #pragma unroll
        for (int kp = 0; kp < 8; ++kp) {
            int fid = ((kp + 4) * 16 + ti) * 64 + lane;
            wl[i][kp] = *reinterpret_cast<const hfrag*>(&wfl[(size_t)fid * 4]);
        }
    }
    #pragma unroll
    for (int i = 0; i < 2; ++i) {
        #pragma unroll
        for (int kb = 0; kb < 12; ++kb) asm volatile("" : "+v"(wh[i][kb]));
        #pragma unroll
        for (int kp = 0; kp < 8; ++kp) asm volatile("" : "+v"(wl[i][kp]));
    }

    // bias folded into MFMA C-init
    f4v bcv[2];
    #pragma unroll
    for (int i = 0; i < 2; ++i)
        #pragma unroll
        for (int r = 0; r < 4; ++r) {
            int n = (2 * w + i) * 16 + 4 * q + r;
            bcv[i][r] = b_ih[n] + b_hh[n];
        }
    const int len_c = x_len[rb + col];
    int tmax = len_c;
    #pragma unroll
    for (int m = 1; m < 16; m <<= 1) {
        int o = __shfl_xor(tmax, m, 64);
        tmax = tmax > o ? tmax : o;
    }

    // token table, transposed [t*16 + m]
    for (int u = tid; u < Mrows * Sv; u += 512) {
        int tt = u & 63, m = u >> 6;
        sidx[tt * 16 + m] = x_in[(rb + m) * Sv + tt];
    }
    // zero h region of buffer 0 (words 1024..3071; SW permutes within)
    for (int u = tid; u < 2048; u += 512) SH[1024 + u] = 0u;

    // emb staging geometry: thread stages 4 consecutive k of one row (f16 only)
    const int em = tid >> 5;            // row 0..15
    const int ek = (tid & 31) * 4;      // k 0..124
    const int eo = (ek >> 5) * 256 + ((((ek >> 3) & 3) * 16 + em) * 4) + (((ek >> 2) & 1) * 2);

    // stage emb for t=0; prefetch row for t=1 (depth-2 pipeline)
    {
        int tok0 = x_in[(rb + em) * Sv + 0];
        float4 e0 = *(const float4*)&emb[(size_t)tok0 * Ev + ek];
        *reinterpret_cast<uint2*>(&SH[SW(eo)]) =
            make_uint2(pk_h2(e0.x, e0.y), pk_h2(e0.z, e0.w));
    }
    float4 ev_cur;
    {
        int tok1 = x_in[(rb + em) * Sv + 1];
        ev_cur = *(const float4*)&emb[(size_t)tok1 * Ev + ek];
    }
    __syncthreads();

    #pragma unroll 1
    for (int t = 0; t < tmax; ++t) {
        const int rbuf = (t & 1) * WRDS;
        const int wbuf = ((t + 1) & 1) * WRDS;

        // prefetch emb row for t+2 (full step of latency budget)
        float4 ev_next;
        if (t + 2 < Sv) {
            int tok = sidx[(t + 2) * 16 + em];
            ev_next = *(const float4*)&emb[(size_t)tok * Ev + ek];
        }

        // 6 accumulator chains: hi even/odd per tile + lo per tile
        f4v aHe0 = bcv[0], aHe1 = bcv[1];
        f4v z = {0.f, 0.f, 0.f, 0.f};
        f4v aHo0 = z, aHo1 = z, aL0 = z, aL1 = z;

        #pragma unroll
        for (int kb = 0; kb < 4; ++kb) {
            hfrag ah = *reinterpret_cast<const hfrag*>(&SH[rbuf + SW(kb * 256 + lane * 4)]);
            if (kb & 1) {
                aHo0 = __builtin_amdgcn_mfma_f32_16x16x32_f16(wh[0][kb], ah, aHo0, 0, 0, 0);
                aHo1 = __builtin_amdgcn_mfma_f32_16x16x32_f16(wh[1][kb], ah, aHo1, 0, 0, 0);
            } else {
                aHe0 = __builtin_amdgcn_mfma_f32_16x16x32_f16(wh[0][kb], ah, aHe0, 0, 0, 0);
                aHe1 = __builtin_amdgcn_mfma_f32_16x16x32_f16(wh[1][kb], ah, aHe1, 0, 0, 0);
            }
        }
        #pragma unroll
        for (int kb = 4; kb < 12; ++kb) {
            hfrag ah = *reinterpret_cast<const hfrag*>(&SH[rbuf + SW(kb * 256 + lane * 4)]);
            if (kb & 1) {
                aHo0 = __builtin_amdgcn_mfma_f32_16x16x32_f16(wh[0][kb], ah, aHo0, 0, 0, 0);
                aHo1 = __builtin_amdgcn_mfma_f32_16x16x32_f16(wh[1][kb], ah, aHo1, 0, 0, 0);
            } else {
                aHe0 = __builtin_amdgcn_mfma_f32_16x16x32_f16(wh[0][kb], ah, aHe0, 0, 0, 0);
                aHe1 = __builtin_amdgcn_mfma_f32_16x16x32_f16(wh[1][kb], ah, aHe1, 0, 0, 0);
            }
            aL0 = __builtin_amdgcn_mfma_f32_16x16x32_f16(wl[0][kb - 4], ah, aL0, 0, 0, 0);
            aL1 = __builtin_amdgcn_mfma_f32_16x16x32_f16(wl[1][kb - 4], ah, aL1, 0, 0, 0);
        }

        // epilogue: lane holds h[m=col][n = ti*16 + 4q + r]
        #pragma unroll
        for (int i = 0; i < 2; ++i) {
            f4v s  = (i == 0) ? (aHe0 + aHo0) : (aHe1 + aHo1);
            f4v sl = (i == 0) ? aL0 : aL1;
            const int ti = 2 * w + i;
            float hv[4];
            #pragma unroll
            for (int r = 0; r < 4; ++r)
                hv[r] = fast_tanh(s[r] + sl[r] * LO_DESCALE);
            const int dl = ((ti & 1) * 2 + (q >> 1)) * 16 + col;
            const uint2 hu = make_uint2(pk_h2(hv[0], hv[1]), pk_h2(hv[2], hv[3]));
            const int oAH = (4 + (ti >> 1)) * 256 + dl * 4 + (q & 1) * 2;
            *reinterpret_cast<uint2*>(&SH[wbuf + SW(oAH)]) = hu;
            if (t == len_c - 1) {
                const int oLH = (ti >> 1) * 256 + dl * 4 + (q & 1) * 2;
                *reinterpret_cast<uint2*>(&LF[SW(oLH)]) = hu;
            }
        }
        // stage emb for step t+1 (value prefetched at t-1)
        if (t + 1 < Sv) {
            *reinterpret_cast<uint2*>(&SH[wbuf + SW(eo)]) =
                make_uint2(pk_h2(ev_cur.x, ev_cur.y), pk_h2(ev_cur.z, ev_cur.w));
        }
        ev_cur = ev_next;
        __syncthreads();
    }

    // ---- fused FC1 (MFMA, f16 hi+lo) on LF ----
    f4v fH0, fH1, fL0, fL1;
    {
        float4 bb0 = *(const float4*)&b1[(2 * w) * 16 + 4 * q];
        float4 bb1 = *(const float4*)&b1[(2 * w + 1) * 16 + 4 * q];
        fH0 = (f4v){bb0.x, bb0.y, bb0.z, bb0.w};
        fH1 = (f4v){bb1.x, bb1.y, bb1.z, bb1.w};
        f4v z = {0.f, 0.f, 0.f, 0.f};
        fL0 = z; fL1 = z;
    }
    #pragma unroll
    for (int kb = 0; kb < 8; ++kb) {
        hfrag ah = *reinterpret_cast<const hfrag*>(&LF[SW(kb * 256 + lane * 4)]);
        int fid0 = (kb * 16 + 2 * w) * 64 + lane;
        int fid1 = fid0 + 64;
        hfrag w0h = *reinterpret_cast<const hfrag*>(&wf1h[(size_t)fid0 * 4]);
        hfrag w1h = *reinterpret_cast<const hfrag*>(&wf1h[(size_t)fid1 * 4]);
        hfrag w0l = *reinterpret_cast<const hfrag*>(&wf1l[(size_t)fid0 * 4]);
        hfrag w1l = *reinterpret_cast<const hfrag*>(&wf1l[(size_t)fid1 * 4]);
        fH0 = __builtin_amdgcn_mfma_f32_16x16x32_f16(w0h, ah, fH0, 0, 0, 0);
        fH1 = __builtin_amdgcn_mfma_f32_16x16x32_f16(w1h, ah, fH1, 0, 0, 0);
        fL0 = __builtin_amdgcn_mfma_f32_16x16x32_f16(w0l, ah, fL0, 0, 0, 0);
        fL1 = __builtin_amdgcn_mfma_f32_16x16x32_f16(w1l, ah, fL1, 0, 0, 0);
    }

    // y = relu(...) into yb (aliases SH; step buffers dead here)
    #pragma unroll
    for (int i = 0; i < 2; ++i) {
        int n0 = (2 * w + i) * 16 + 4 * q;
        f4v s = (i == 0) ? fH0 : fH1;
        f4v sl = (i == 0) ? fL0 : fL1;
        float4 yv;
        yv.x = fmaxf(s[0] + sl[0] * LO_DESCALE, 0.f);
        yv.y = fmaxf(s[1] + sl[1] * LO_DESCALE, 0.f);
        yv.z = fmaxf(s[2] + sl[2] * LO_DESCALE, 0.f);
        yv.w = fmaxf(s[3] + sl[3] * LO_DESCALE, 0.f);
        *reinterpret_cast<float4*>(&yb[col * 260 + n0]) = yv;
    }
    __syncthreads();

    // ---- FC2: 16 x 18 dots of length 256 ----
    if (tid < Mrows * Cv) {
        int r = tid & 15, cc = tid >> 4;
        float s = b2[cc];
        #pragma unroll 8
        for (int k4 = 0; k4 < Hv / 4; ++k4) {
            float4 yv = *reinterpret_cast<const float4*>(&yb[r * 260 + 4 * k4]);
            float4 wv2 = *(const float4*)&W2[cc * Hv + 4 * k4];
            s = fmaf(yv.x, wv2.x, s);
            s = fmaf(yv.y, wv2.y, s);
            s = fmaf(yv.z, wv2.z, s);
            s = fmaf(yv.w, wv2.w, s);
        }
        out[(rb + r) * Cv + cc] = s;
    }
}

extern "C" void kernel_launch(void* const* d_in, const int* in_sizes, int n_in,
                              void* d_out, int out_size, void* d_ws, size_t ws_size,
                              hipStream_t stream) {
    const int*   x_in  = (const int*)  d_in[0];
    const int*   x_len = (const int*)  d_in[1];
    const float* emb   = (const float*)d_in[2];
    const float* W_ih  = (const float*)d_in[3];
    const float* W_hh  = (const float*)d_in[4];
    const float* b_ih  = (const float*)d_in[5];
    const float* b_hh  = (const float*)d_in[6];
    const float* W1    = (const float*)d_in[7];
    const float* b1    = (const float*)d_in[8];
    const float* W2    = (const float*)d_in[9];
    const float* b2    = (const float*)d_in[10];
    float* out = (float*)d_out;

    unsigned* wfh  = (unsigned*)d_ws;         // 12288 frags * 16 B
    unsigned* wfl  = wfh  + 12288 * 4;        // 12288 * 16 B
    unsigned* wf1h = wfl  + 12288 * 4;        // 8192 * 16 B
    unsigned* wf1l = wf1h + 8192 * 4;         // 8192 * 16 B

    build_frags<<<80, 256, 0, stream>>>(W_ih, W_hh, W1, wfh, wfl, wf1h, wf1l);
    rnn_fused<<<Bv / Mrows, 512, 0, stream>>>(x_in, x_len, emb, wfh, wfl,
                                              wf1h, wf1l, b_ih, b_hh,
                                              b1, W2, b2, out);
}